// Round 4
// baseline (1686.439 us; speedup 1.0000x reference)
//
#include <hip/hip_runtime.h>
#include <stdint.h>

#define H 4096

typedef float v4f __attribute__((ext_vector_type(4)));
typedef long long i64;
typedef long long v2l __attribute__((ext_vector_type(2)));

// Fragment-ordered fp8 layout: 16-B chunk (row n, block kb, chunk c) lives at
//   (n>>4)*65536 + kb*2048 + c*256 + (n&15)*16
// where chunk c / intra-chunk byte mapping of original k (within kb):
//   b = ks2*32 + q*8 + j  ->  c = 2*q + (ks2>>1), intra = (ks2&1)*8 + j
// (identical byte content to rounds 2/3, which passed; only addresses moved)

// ---- weights: fp32 [k][n] -> fp8 fragment-ordered [n-group][kb][c][l16] ----
__global__ __launch_bounds__(256) void conv_w_kernel(
    const float* __restrict__ w0, const float* __restrict__ w1,
    const float* __restrict__ w2, uint8_t* __restrict__ o0,
    uint8_t* __restrict__ o1, uint8_t* __restrict__ o2) {
  const float* w = (blockIdx.z == 0) ? w0 : (blockIdx.z == 1 ? w1 : w2);
  uint8_t* o = (blockIdx.z == 0) ? o0 : (blockIdx.z == 1 ? o1 : o2);
  __shared__ __attribute__((aligned(16))) uint8_t buf[64 * 136];
  const int tid = threadIdx.x;
  const int k0 = blockIdx.y * 128, n0 = blockIdx.x * 64;
  const int kbY = blockIdx.y;
  const int n4 = tid & 15, krun = tid >> 4;

  unsigned dw[8];
#pragma unroll
  for (int i = 0; i < 8; ++i) {
    v4f f = *(const v4f*)(w + (size_t)(k0 + krun * 8 + i) * H + n0 + n4 * 4);
    unsigned p = __builtin_amdgcn_cvt_pk_fp8_f32(f.x, f.y, 0, false);
    dw[i] = __builtin_amdgcn_cvt_pk_fp8_f32(f.z, f.w, p, true);
  }
#pragma unroll
  for (int b = 0; b < 4; ++b) {
    const unsigned sel1 = 0x0c0c0000u | ((4u + b) << 8) | (unsigned)b;
    unsigned p01 = __builtin_amdgcn_perm(dw[1], dw[0], sel1);
    unsigned p23 = __builtin_amdgcn_perm(dw[3], dw[2], sel1);
    unsigned lo = __builtin_amdgcn_perm(p23, p01, 0x05040100u);
    unsigned p45 = __builtin_amdgcn_perm(dw[5], dw[4], sel1);
    unsigned p67 = __builtin_amdgcn_perm(dw[7], dw[6], sel1);
    unsigned hi = __builtin_amdgcn_perm(p67, p45, 0x05040100u);
    uint2 kk; kk.x = lo; kk.y = hi;
    *(uint2*)(buf + (n4 * 4 + b) * 136 + krun * 8) = kk;
  }
  __syncthreads();

  // pass 2: chunk c of 16 permuted bytes = k-runs (8*(c&1)+(c>>1)) and +4
#pragma unroll
  for (int it = 0; it < 2; ++it) {
    const int id = it * 256 + tid;
    const int n = id >> 3, c = id & 7;
    const int r0 = 8 * (c & 1) + (c >> 1);
    uint2 a = *(const uint2*)(buf + n * 136 + r0 * 8);
    uint2 b = *(const uint2*)(buf + n * 136 + (r0 + 4) * 8);
    uint4 outv; outv.x = a.x; outv.y = a.y; outv.z = b.x; outv.w = b.y;
    const int nn = n0 + n;
    *(uint4*)(o + (((size_t)(nn >> 4)) << 16) + (size_t)kbY * 2048 + c * 256 +
              (nn & 15) * 16) = outv;
  }
}

// ---- row kernel: (optional relu) + rmsnorm + group-128 fp8 quant ----
// 16 rows per block, 512 threads: thread owns one whole 128-col scale group.
// Emits fragment-ordered qa + transposed scales sxT[kb][m].
__global__ __launch_bounds__(512) void quant_kernel(
    const float* in, const float* __restrict__ nw, uint8_t* __restrict__ q,
    float* __restrict__ sxT, const int relu) {
  const int tid = threadIdx.x;
  const int r = tid & 15, kb = tid >> 4;  // kb in [0,32)
  const int row = blockIdx.x * 16 + r;
  const float* rp = in + (size_t)row * H + kb * 128;

  v4f v[32];
  float ss = 0.f;
#pragma unroll
  for (int i = 0; i < 32; ++i) {
    v4f x = *(const v4f*)(rp + i * 4);
    if (relu) {
      x.x = fmaxf(x.x, 0.f); x.y = fmaxf(x.y, 0.f);
      x.z = fmaxf(x.z, 0.f); x.w = fmaxf(x.w, 0.f);
    }
    v[i] = x;
    ss += x.x * x.x + x.y * x.y + x.z * x.z + x.w * x.w;
  }
  // reduce over the 32 kb-threads of this row
  ss += __shfl_xor(ss, 16);
  ss += __shfl_xor(ss, 32);
  __shared__ float red[8][16];
  if ((tid & 63) < 16) red[tid >> 6][tid & 15] = ss;
  __syncthreads();
  float tot = 0.f;
#pragma unroll
  for (int w8 = 0; w8 < 8; ++w8) tot += red[w8][r];
  const float rinv = 1.f / sqrtf(tot * (1.f / H) + 1e-6f);

  const float* np = nw + kb * 128;
  float am = 0.f;
#pragma unroll
  for (int i = 0; i < 32; ++i) {
    v4f nv = *(const v4f*)(np + i * 4);
    v4f y = v[i] * rinv * nv;
    v[i] = y;
    am = fmaxf(am, fmaxf(fmaxf(fabsf(y.x), fabsf(y.y)),
                         fmaxf(fabsf(y.z), fabsf(y.w))));
  }
  const float s = fmaxf(am, 1e-12f) / 448.f;  // exact: matches reference
  unsigned dw[8][4];
#pragma unroll
  for (int u = 0; u < 8; ++u) {
#pragma unroll
    for (int k4 = 0; k4 < 4; ++k4) {
      v4f y = v[u * 4 + k4];
      unsigned p = __builtin_amdgcn_cvt_pk_fp8_f32(y.x / s, y.y / s, 0, false);
      dw[u][k4] = __builtin_amdgcn_cvt_pk_fp8_f32(y.z / s, y.w / s, p, true);
    }
  }
  uint8_t* qb = q + (((size_t)blockIdx.x) << 16) + kb * 2048 + r * 16;
#pragma unroll
  for (int c = 0; c < 8; ++c) {
    const int ua = (c >> 2) + 4 * (c & 1);  // contributes intra bytes 0..7
    const int ub = ua + 2;                  // contributes intra bytes 8..15
    const int vs = ((c >> 1) & 1) * 2;      // lo/hi v-half dword pair
    uint4 st;
    st.x = dw[ua][vs]; st.y = dw[ua][vs + 1];
    st.z = dw[ub][vs]; st.w = dw[ub][vs + 1];
    *(uint4*)(qb + c * 256) = st;
  }
  sxT[(size_t)kb * 4096 + row] = s;
}

// ---- final rmsnorm, in-place on d_out ----
__global__ __launch_bounds__(256) void norm_kernel(float* io,
                                                   const float* __restrict__ nw) {
  const int row = blockIdx.x, tid = threadIdx.x;
  v4f* rp = (v4f*)(io + (size_t)row * H);
  v4f v[4];
  float ss = 0.f;
#pragma unroll
  for (int j = 0; j < 4; ++j) {
    v4f x = rp[j * 256 + tid];
    v[j] = x;
    ss += x.x * x.x + x.y * x.y + x.z * x.z + x.w * x.w;
  }
#pragma unroll
  for (int o = 32; o > 0; o >>= 1) ss += __shfl_down(ss, o);
  __shared__ float red[4];
  if ((tid & 63) == 0) red[tid >> 6] = ss;
  __syncthreads();
  ss = red[0] + red[1] + red[2] + red[3];
  const float rinv = 1.f / sqrtf(ss * (1.f / H) + 1e-6f);
#pragma unroll
  for (int j = 0; j < 4; ++j) {
    v4f nv = ((const v4f*)nw)[j * 256 + tid];
    v4f y;
    y.x = v[j].x * rinv * nv.x;
    y.y = v[j].y * rinv * nv.y;
    y.z = v[j].z * rinv * nv.z;
    y.w = v[j].w * rinv * nv.w;
    rp[j * 256 + tid] = y;
  }
}

// ---- barrier-free fp8 GEMM: fragments loaded global->VGPR, no LDS ----
__global__ __launch_bounds__(256, 2) void gemm_kernel(
    const uint8_t* __restrict__ qa,   // fragment-ordered activations
    const float* __restrict__ sxT,    // [32][M] act scales
    const uint8_t* __restrict__ wt,   // fragment-ordered weights
    const float* __restrict__ ws,     // [32][32] weight scales [kb][nb]
    const float* resid, float* outp, const int relu) {
  const int tid = threadIdx.x;
  const int wv = tid >> 6, lane = tid & 63;
  const int quad = lane >> 4, l16 = lane & 15;
  const int wm = wv >> 1, wn = wv & 1;
  const int coff = quad * 512 + l16 * 16;  // chunk (quad*2) base for this lane

  const uint8_t* Abase = qa + (((size_t)(blockIdx.y * 8 + wm * 4)) << 16) + coff;
  const uint8_t* Bbase = wt + (((size_t)(blockIdx.x * 8 + wn * 4)) << 16) + coff;
  const float* Sbase = sxT + blockIdx.y * 128 + wm * 64 + quad * 4;
  const float* wsp = ws + blockIdx.x;

  const v4f zf = {0.f, 0.f, 0.f, 0.f};
  v4f acc[4][4];
#pragma unroll
  for (int i = 0; i < 4; ++i)
#pragma unroll
    for (int j = 0; j < 4; ++j) acc[i][j] = zf;

  v2l Af0[4][2], Bf0[4][2], Af1[4][2], Bf1[4][2];
  v4f Sf0[4], Sf1[4];

#define LOADSET(AF, BF, SF, KB)                                         \
  do {                                                                  \
    const size_t ko = (size_t)(KB) * 2048;                              \
    const float* sp = Sbase + (size_t)(KB) * 4096;                      \
    _Pragma("unroll") for (int t = 0; t < 4; ++t) {                     \
      AF[t][0] = *(const v2l*)(Abase + ((size_t)t << 16) + ko);         \
      AF[t][1] = *(const v2l*)(Abase + ((size_t)t << 16) + ko + 256);   \
      BF[t][0] = *(const v2l*)(Bbase + ((size_t)t << 16) + ko);         \
      BF[t][1] = *(const v2l*)(Bbase + ((size_t)t << 16) + ko + 256);   \
      SF[t] = *(const v4f*)(sp + t * 16);                               \
    }                                                                   \
  } while (0)

#define STEPSET(AF, BF, SF, KB)                                                        \
  do {                                                                                 \
    const float wsk = wsp[(KB) * 32];                                                  \
    _Pragma("unroll") for (int tr = 0; tr < 4; ++tr) {                                 \
      const v4f s4 = SF[tr] * wsk;                                                     \
      _Pragma("unroll") for (int tc = 0; tc < 4; ++tc) {                               \
        v4f p = __builtin_amdgcn_mfma_f32_16x16x32_fp8_fp8(AF[tr][0].x, BF[tc][0].x,   \
                                                           zf, 0, 0, 0);               \
        p = __builtin_amdgcn_mfma_f32_16x16x32_fp8_fp8(AF[tr][0].y, BF[tc][0].y, p,    \
                                                       0, 0, 0);                       \
        p = __builtin_amdgcn_mfma_f32_16x16x32_fp8_fp8(AF[tr][1].x, BF[tc][1].x, p,    \
                                                       0, 0, 0);                       \
        p = __builtin_amdgcn_mfma_f32_16x16x32_fp8_fp8(AF[tr][1].y, BF[tc][1].y, p,    \
                                                       0, 0, 0);                       \
        acc[tr][tc] += p * s4;                                                         \
      }                                                                                \
    }                                                                                  \
  } while (0)

  LOADSET(Af0, Bf0, Sf0, 0);
#pragma unroll 1
  for (int kb = 0; kb < 32; kb += 2) {
    LOADSET(Af1, Bf1, Sf1, kb + 1);
    STEPSET(Af0, Bf0, Sf0, kb);
    if (kb + 2 < 32) LOADSET(Af0, Bf0, Sf0, kb + 2);
    STEPSET(Af1, Bf1, Sf1, kb + 1);
  }
#undef LOADSET
#undef STEPSET

  // epilogue: add residual (relu(x) for layer 0)
  const int mB = blockIdx.y * 128 + wm * 64 + quad * 4;
  const int nB = blockIdx.x * 128 + wn * 64 + l16;
#pragma unroll
  for (int tr = 0; tr < 4; ++tr) {
#pragma unroll
    for (int r = 0; r < 4; ++r) {
      const size_t rowOff = (size_t)(mB + tr * 16 + r) * H;
#pragma unroll
      for (int tc = 0; tc < 4; ++tc) {
        const size_t idx = rowOff + nB + tc * 16;
        float rv = resid[idx];
        if (relu) rv = fmaxf(rv, 0.f);
        outp[idx] = acc[tr][tc][r] + rv;
      }
    }
  }
}

extern "C" void kernel_launch(void* const* d_in, const int* in_sizes, int n_in,
                              void* d_out, int out_size, void* d_ws, size_t ws_size,
                              hipStream_t stream) {
  const float* x   = (const float*)d_in[0];
  const float* w0  = (const float*)d_in[1];
  const float* ws0 = (const float*)d_in[2];
  const float* w1  = (const float*)d_in[3];
  const float* ws1 = (const float*)d_in[4];
  const float* w2  = (const float*)d_in[5];
  const float* ws2 = (const float*)d_in[6];
  const float* nw0 = (const float*)d_in[7];
  const float* nw1 = (const float*)d_in[8];
  const float* nw2 = (const float*)d_in[9];
  const float* nw3 = (const float*)d_in[10];
  float* R = (float*)d_out;  // residual lives in d_out (in-place)

  uint8_t* base = (uint8_t*)d_ws;
  uint8_t* wq0 = base;
  uint8_t* wq1 = base + ((size_t)16 << 20);
  uint8_t* wq2 = base + ((size_t)32 << 20);
  uint8_t* qa  = base + ((size_t)48 << 20);
  float* sa    = (float*)(base + ((size_t)64 << 20));  // sxT[32][4096]

  conv_w_kernel<<<dim3(64, 32, 3), 256, 0, stream>>>(w0, w1, w2, wq0, wq1, wq2);

  quant_kernel<<<256, 512, 0, stream>>>(x, nw0, qa, sa, 1);
  gemm_kernel<<<dim3(32, 32), 256, 0, stream>>>(qa, sa, wq0, ws0, x, R, 1);

  quant_kernel<<<256, 512, 0, stream>>>(R, nw1, qa, sa, 0);
  gemm_kernel<<<dim3(32, 32), 256, 0, stream>>>(qa, sa, wq1, ws1, R, R, 0);

  quant_kernel<<<256, 512, 0, stream>>>(R, nw2, qa, sa, 0);
  gemm_kernel<<<dim3(32, 32), 256, 0, stream>>>(qa, sa, wq2, ws2, R, R, 0);

  norm_kernel<<<4096, 256, 0, stream>>>(R, nw3);
}